// Round 11
// baseline (223.321 us; speedup 1.0000x reference)
//
#include <hip/hip_runtime.h>
#include <cstdint>

// ---------------- problem constants ----------------
#define NIMG  16
#define NCLS  80
#define HH    100
#define WW    152
#define HWSZ  (HH*WW)          // 15200
#define HW4   (HWSZ/4)         // 3800
#define NE    (HWSZ*NCLS)      // 1216000
#define KTOP  1000
#define POSTN 100
#define PRE_T 0.05f
#define NMS_T 0.6f
#define FLOOR_KEY 0x3D000000u
#define FLOOR_BIN 976
#define SEL_CAP   2048
#define NTILE 240              // 64-elem chunks per class (238 real + 2 zero-padded)
#define NCHUNK (NCLS*NTILE)    // 19200 chunks per image
#define NSL1  20               // hist1 slices (4 classes each)
#define NSL2  8                // collect slices (2400 chunks each)
#define SCAP  2048             // candidates cap per collect slice
#define MSLICE 4               // mask slices per image (250 rows each); 64 blocks = 1/CU
#define MRPS 250               // mask rows per slice

// ---------------- workspace layout (bytes), ~9.6 MB ----------------
#define OFF_H1S   0u         // u16 [16][20][4096]
#define OFF_H2S   2621440u   // u16 [16][8][4096]
#define OFF_CANDS 3670016u   // u64 [16][8][2048]
#define OFF_CCNT  5767168u   // u32 [16][8]
#define OFF_CMAX  5767680u   // u32 [16][19200]
#define OFF_BOX   6996480u   // f32 [16][1000][4]
#define OFF_SC    7252480u   // f32 [16][1000]
#define OFF_LAB   7316480u   // i32 [16][1000]
#define OFF_MASK  7380480u   // u64 [16][1000][16]
#define OFF_COLS  9428480u   // u64 [16][16][64]

__device__ __forceinline__ float sigm(float x) { return 1.f / (1.f + expf(-x)); }

__device__ __forceinline__ uint64_t shfl64(uint64_t v, int src) {
  int lo = __shfl((int)(uint32_t)(v & 0xffffffffu), src, 64);
  int hi = __shfl((int)(uint32_t)(v >> 32), src, 64);
  return ((uint64_t)(uint32_t)hi << 32) | (uint32_t)lo;
}
__device__ __forceinline__ uint64_t shfl64x(uint64_t v, int d) {
  int lo = __shfl_xor((int)(uint32_t)(v & 0xffffffffu), d, 64);
  int hi = __shfl_xor((int)(uint32_t)(v >> 32), d, 64);
  return ((uint64_t)(uint32_t)hi << 32) | (uint32_t)lo;
}

// descending bitonic sort, thread-per-pair: one LDS round-trip per pass
__device__ __forceinline__ void bitonic_desc_tpp(uint64_t* s, int nn, int t, int nt) {
  const int np = nn >> 1;
  for (int k2 = 2; k2 <= nn; k2 <<= 1) {
    for (int j = k2 >> 1; j > 0; j >>= 1) {
      __syncthreads();
      for (int q = t; q < np; q += nt) {
        int i = ((q & ~(j - 1)) << 1) | (q & (j - 1));
        int p = i | j;
        uint64_t a = s[i], b = s[p];
        bool desc = ((i & k2) == 0);
        bool sw = desc ? (a < b) : (a > b);
        if (sw) { s[i] = b; s[p] = a; }
      }
    }
  }
  __syncthreads();
}

// level-1 findbin from an LDS 4096-bin summed histogram (thread 0)
__device__ __forceinline__ void findbin1(const unsigned* hsum, const unsigned* part,
                                         unsigned* thr1_o, unsigned* cumAbove_o) {
  unsigned cum = 0, cumAbove = 0;
  int bin = -1;
  for (int ch = 255; ch >= 0 && bin < 0; --ch) {
    if (cum + part[ch] >= (unsigned)KTOP) {
      for (int i = 15; i >= 0; --i) {
        unsigned v = hsum[ch * 16 + i];
        if (cum + v >= (unsigned)KTOP) { bin = ch * 16 + i; cumAbove = cum; break; }
        cum += v;
      }
    } else cum += part[ch];
  }
  if (bin < 0) { bin = FLOOR_BIN; cumAbove = cum - hsum[FLOOR_BIN]; }
  *thr1_o = (unsigned)bin;
  *cumAbove_o = cumAbove;
}

// ---------------- D1: score histogram slices + per-chunk max keys ----------------
__global__ void __launch_bounds__(1024) k_hist(
    const float4* __restrict__ cls4, const float4* __restrict__ ctr4,
    unsigned short* __restrict__ h1s, unsigned* __restrict__ cmax) {
  __shared__ unsigned h[4096];
  const int n = blockIdx.x, z = blockIdx.y;
  const int t = threadIdx.x;
  for (int i = t; i < 4096; i += 1024) h[i] = 0;
  __syncthreads();
  const float4* cp = cls4 + (size_t)n * (NE / 4);
  const float4* cr = ctr4 + (size_t)n * HW4;
#pragma unroll
  for (int it = 0; it < 4; ++it) {
    const int idx4 = it * 1024 + t;
    const bool val = idx4 < HW4;
    float ct0 = 0, ct1 = 0, ct2 = 0, ct3 = 0;
    if (val) {
      float4 c4 = cr[idx4];
      ct0 = sigm(c4.x); ct1 = sigm(c4.y); ct2 = sigm(c4.z); ct3 = sigm(c4.w);
    }
    const int tile = idx4 >> 4;
    for (int c = z * 4; c < z * 4 + 4; ++c) {
      unsigned k0 = 0, k1 = 0, k2 = 0, k3 = 0;
      if (val) {
        float4 v = cp[c * HW4 + idx4];
        float s0 = sigm(v.x), s1 = sigm(v.y), s2 = sigm(v.z), s3 = sigm(v.w);
        k0 = (s0 > PRE_T) ? __float_as_uint(s0 * ct0) : 0u;
        k1 = (s1 > PRE_T) ? __float_as_uint(s1 * ct1) : 0u;
        k2 = (s2 > PRE_T) ? __float_as_uint(s2 * ct2) : 0u;
        k3 = (s3 > PRE_T) ? __float_as_uint(s3 * ct3) : 0u;
        if (k0 >= FLOOR_KEY) atomicAdd(&h[k0 >> 20], 1u);
        if (k1 >= FLOOR_KEY) atomicAdd(&h[k1 >> 20], 1u);
        if (k2 >= FLOOR_KEY) atomicAdd(&h[k2 >> 20], 1u);
        if (k3 >= FLOOR_KEY) atomicAdd(&h[k3 >> 20], 1u);
      }
      unsigned km = max(max(k0, k1), max(k2, k3));
      km = max(km, (unsigned)__shfl_xor((int)km, 1, 64));
      km = max(km, (unsigned)__shfl_xor((int)km, 2, 64));
      km = max(km, (unsigned)__shfl_xor((int)km, 4, 64));
      km = max(km, (unsigned)__shfl_xor((int)km, 8, 64));
      if ((t & 15) == 0 && tile < NTILE)
        cmax[(size_t)n * NCHUNK + c * NTILE + tile] = km;
    }
  }
  __syncthreads();
  for (int i = t; i < 4096; i += 1024)
    h1s[(size_t)((n * NSL1 + z) << 12) + i] = (unsigned short)h[i];   // <= 60800, fits u16
}

// ---------------- D2: findbin1 + sparse collect into per-slice arrays ----------------
__global__ void __launch_bounds__(1024) k_collect(
    const unsigned short* __restrict__ h1s, const unsigned* __restrict__ cmax,
    const float* __restrict__ cls, const float* __restrict__ ctr,
    uint64_t* __restrict__ candS, unsigned* __restrict__ ccnt,
    unsigned short* __restrict__ h2s) {
  __shared__ unsigned hsum[4096];
  __shared__ unsigned h2L[4096];
  __shared__ unsigned queue[2400];
  __shared__ unsigned part[256];
  __shared__ int qn_s, ccnt_s;
  __shared__ unsigned thr1_s, dum_s;
  const int s = blockIdx.x, n = blockIdx.y;
  const int t = threadIdx.x;
  for (int i = t; i < 4096; i += 1024) {
    unsigned v = 0;
    for (int z = 0; z < NSL1; ++z) v += (unsigned)h1s[(size_t)((n * NSL1 + z) << 12) + i];
    hsum[i] = v;
    h2L[i] = 0;
  }
  if (t == 0) { qn_s = 0; ccnt_s = 0; }
  __syncthreads();
  if (t < 256) {
    unsigned ps = 0;
    for (int i = 0; i < 16; ++i) ps += hsum[t * 16 + i];
    part[t] = ps;
  }
  __syncthreads();
  if (t == 0) findbin1(hsum, part, &thr1_s, &dum_s);
  __syncthreads();
  const unsigned thr1 = thr1_s, thrKey1 = thr1 << 20;
  const int c0 = s * (NCHUNK / NSL2);                 // 2400 chunks per slice
  for (int i = t; i < NCHUNK / NSL2; i += 1024) {
    if (cmax[(size_t)n * NCHUNK + c0 + i] >= thrKey1) {
      int p = atomicAdd(&qn_s, 1);
      queue[p] = (unsigned)(c0 + i);
    }
  }
  __syncthreads();
  const int qn = qn_s;
  const int lane = t & 63, wv = t >> 6;
  for (int qi = wv; qi < qn; qi += 16) {
    int hc = (int)queue[qi];
    int c = hc / NTILE, tile = hc - c * NTILE;
    int hw = tile * 64 + lane;
    if (hw < HWSZ) {
      float s1 = sigm(cls[((size_t)n * NCLS + c) * HWSZ + hw]);
      float sc = sigm(ctr[(size_t)n * HWSZ + hw]);
      unsigned key = (s1 > PRE_T) ? __float_as_uint(s1 * sc) : 0u;
      if (key >= thrKey1) {
        unsigned fidx = (unsigned)(hw * NCLS + c);
        uint64_t comp = ((uint64_t)key << 21) | (uint64_t)(0x1FFFFFu - fidx);
        int p = atomicAdd(&ccnt_s, 1);
        if (p < SCAP) candS[(size_t)(n * NSL2 + s) * SCAP + p] = comp;
        if ((key >> 20) == thr1) atomicAdd(&h2L[(key >> 8) & 0xFFFu], 1u);
      }
    }
  }
  __syncthreads();
  for (int i = t; i < 4096; i += 1024)
    h2s[(size_t)((n * NSL2 + s) << 12) + i] = (unsigned short)h2L[i];
  if (t == 0) ccnt[n * NSL2 + s] = (unsigned)min(ccnt_s, SCAP);
}

// ---- D3: redundant select/decode per slice + parallel IoU mask (4 blocks/image) ----
__global__ void __launch_bounds__(1024) k_selmask(
    const unsigned short* __restrict__ h1s, const unsigned short* __restrict__ h2s,
    const uint64_t* __restrict__ candS, const unsigned* __restrict__ ccnt,
    const float* __restrict__ locations, const float* __restrict__ breg,
    const int* __restrict__ imsz,
    float* __restrict__ boxes, float* __restrict__ scw, int* __restrict__ labw,
    uint64_t* __restrict__ masks, uint64_t* __restrict__ colsg) {
  __shared__ unsigned hsum[4096];     // 16 KB (dead after findbin1)
  __shared__ unsigned h2sum[4096];    // 16 KB (dead after findbin2)
  __shared__ uint64_t sel[SEL_CAP];   // 16 KB (dead after decode)
  __shared__ float4 obs[KTOP];        // 16 KB (live through mask phase)
  __shared__ unsigned part[256];
  __shared__ int cnt2_s;
  __shared__ unsigned thr1_s, cumAbove_s, thrKey2_s;
  const int slice = blockIdx.x, n = blockIdx.y;
  const int t = threadIdx.x;
  const int lane = t & 63, wv = t >> 6;

  // ---- sum hist slices ----
  for (int i = t; i < 4096; i += 1024) {
    unsigned v1 = 0, v2 = 0;
    for (int z = 0; z < NSL1; ++z) v1 += (unsigned)h1s[(size_t)((n * NSL1 + z) << 12) + i];
    for (int z = 0; z < NSL2; ++z) v2 += (unsigned)h2s[(size_t)((n * NSL2 + z) << 12) + i];
    hsum[i] = v1;
    h2sum[i] = v2;
  }
  if (t == 0) cnt2_s = 0;
  __syncthreads();
  // ---- findbin level 1 ----
  if (t < 256) {
    unsigned ps = 0;
    for (int i = 0; i < 16; ++i) ps += hsum[t * 16 + i];
    part[t] = ps;
  }
  __syncthreads();
  if (t == 0) findbin1(hsum, part, &thr1_s, &cumAbove_s);
  __syncthreads();
  const unsigned thr1 = thr1_s;
  // ---- findbin level 2 ----
  if (t < 256) {
    unsigned ps = 0;
    for (int i = 0; i < 16; ++i) ps += h2sum[t * 16 + i];
    part[t] = ps;
  }
  __syncthreads();
  if (t == 0) {
    int need = (int)KTOP - (int)cumAbove_s;   // >= 1
    unsigned cum = 0;
    int b2 = -1;
    for (int ch = 255; ch >= 0 && b2 < 0; --ch) {
      if ((int)(cum + part[ch]) >= need) {
        for (int i = 15; i >= 0; --i) {
          unsigned v = h2sum[ch * 16 + i];
          if ((int)(cum + v) >= need) { b2 = ch * 16 + i; break; }
          cum += v;
        }
      } else cum += part[ch];
    }
    thrKey2_s = (b2 < 0) ? (thr1 << 20) : ((thr1 << 20) | ((unsigned)b2 << 8));
  }
  __syncthreads();
  const unsigned thrKey2 = thrKey2_s;

  // ---- gather candidate slices into sel ----
  for (int s = 0; s < NSL2; ++s) {
    const int cn = (int)min(ccnt[n * NSL2 + s], (unsigned)SCAP);
    for (int j = t; j < cn; j += 1024) {
      uint64_t comp = candS[(size_t)(n * NSL2 + s) * SCAP + j];
      if ((unsigned)(comp >> 21) >= thrKey2) {
        int p = atomicAdd(&cnt2_s, 1);
        if (p < SEL_CAP) sel[p] = comp;
      }
    }
  }
  __syncthreads();
  const int m = min(cnt2_s, SEL_CAP);
  for (int j = m + t; j < SEL_CAP; j += 1024) sel[j] = 0;
  __syncthreads();
  bitonic_desc_tpp(sel, SEL_CAP, t, 1024);
  const int nv = min(m, KTOP);

  // ---- decode boxes (t<1000 one item each); slice 0 writes globals ----
  const float hi = (float)imsz[n * 2 + 0];
  const float wi = (float)imsz[n * 2 + 1];
  const float offmul = fmaxf(wi, hi) + 1.0f;
  if (t < KTOP) {
    const int k = t;
    float x1 = 0, y1 = 0, x2 = 0, y2 = 0, ox1 = 0, oy1 = 0, ox2 = 0, oy2 = 0, s = 0;
    int lab = 0;
    if (k < nv) {
      uint64_t comp = sel[k];
      unsigned key = (unsigned)(comp >> 21);
      unsigned idx = 0x1FFFFFu - (unsigned)(comp & 0x1FFFFFu);
      int hw = (int)(idx / NCLS);
      int c  = (int)(idx - (unsigned)hw * NCLS);
      lab = c + 1;
      float lx = locations[hw * 2 + 0];
      float ly = locations[hw * 2 + 1];
      const float* rg = breg + (size_t)n * 4 * HWSZ;
      float rl = rg[hw], rt = rg[HWSZ + hw], rr = rg[2 * HWSZ + hw], rb = rg[3 * HWSZ + hw];
      x1 = fminf(fmaxf(lx - rl, 0.f), wi - 1.f);
      x2 = fminf(fmaxf(lx + rr, 0.f), wi - 1.f);
      y1 = fminf(fmaxf(ly - rt, 0.f), hi - 1.f);
      y2 = fminf(fmaxf(ly + rb, 0.f), hi - 1.f);
      float off = (float)lab * offmul;
      asm volatile("" : "+v"(off));      // keep the rounded off, forbid fma fusion
      ox1 = x1 + off; oy1 = y1 + off; ox2 = x2 + off; oy2 = y2 + off;
      s = sqrtf(__uint_as_float(key));
    }
    if (slice == 0) {
      size_t bb = (size_t)(n * KTOP + k);
      boxes[bb * 4 + 0] = x1; boxes[bb * 4 + 1] = y1;
      boxes[bb * 4 + 2] = x2; boxes[bb * 4 + 3] = y2;
      scw[bb] = s;
      labw[bb] = lab;
    }
    obs[k] = make_float4(ox1, oy1, ox2, oy2);
  }
  __syncthreads();

  // ---- IoU mask for this slice's 250 rows -> global masks + diagonal columns ----
  for (int rr = wv; rr < MRPS; rr += 16) {
    const int r = slice * MRPS + rr;
    if (r >= nv) continue;                       // wave-uniform branch
    const float4 bi = obs[r];
    float areai = (bi.z - bi.x) * (bi.w - bi.y);
    asm volatile("" : "+v"(areai));
    const int Wr = r >> 6;
    uint64_t* mr = masks + ((size_t)n * KTOP + r) * 16;
    for (int w = 0; w < 16; ++w) {
      int j = (w << 6) + lane;
      bool over = false;
      if (j < nv && j != r) {
        float4 bj = obs[j];
        float areaj = (bj.z - bj.x) * (bj.w - bj.y);
        asm volatile("" : "+v"(areaj));
        float ltx = fmaxf(bi.x, bj.x), lty = fmaxf(bi.y, bj.y);
        float rbx = fminf(bi.z, bj.z), rby = fminf(bi.w, bj.w);
        float wx = fmaxf(rbx - ltx, 0.f), wy = fmaxf(rby - lty, 0.f);
        float inter = wx * wy;
        asm volatile("" : "+v"(inter));
        float denom = areai + areaj - inter + 1e-9f;
        over = (inter / denom) > NMS_T;
      }
      uint64_t bu = __ballot(over && (j > r));
      if (lane == 0) mr[w] = bu;
      if (w == Wr) {
        uint64_t bc = __ballot(over && (j < r));   // column via IoU symmetry
        if (lane == 0) colsg[((size_t)n * 16 + w) * 64 + (r & 63)] = bc;
      }
    }
  }
}

// -------- D4: ballot fixed-point greedy scan + top-100 sort + output (16 blocks) --------
__global__ void __launch_bounds__(1024) k_scanout(
    const uint64_t* __restrict__ masks, const uint64_t* __restrict__ colsg,
    const float* __restrict__ boxes, const float* __restrict__ scw,
    const int* __restrict__ labw, float* __restrict__ out) {
  __shared__ uint64_t shmP[KTOP * 17];   // 136,000 B; reused as sel after scan
  __shared__ uint64_t keepb[16];
  __shared__ int nv_s;
  const int n = blockIdx.x;
  const int t = threadIdx.x;
  const int lane = t & 63;
  if (t == 0) nv_s = 0;
  __syncthreads();
  if (t < KTOP) {
    if (scw[(size_t)n * KTOP + t] > 0.f) atomicAdd(&nv_s, 1);
  }
  // stage 1000x16 words, padded rows (stride 17)
  const ulonglong2* src = (const ulonglong2*)(masks + (size_t)n * KTOP * 16);
  for (int j2 = t; j2 < KTOP * 8; j2 += 1024) {
    ulonglong2 v = src[j2];
    int row = j2 >> 3, wp = (j2 & 7) << 1;
    shmP[row * 17 + wp] = v.x;
    shmP[row * 17 + wp + 1] = v.y;
  }
  __syncthreads();
  const int nv = nv_s;
  if (t < 64) {
    uint64_t colr[16];
#pragma unroll
    for (int W = 0; W < 16; ++W) colr[W] = colsg[((size_t)n * 16 + W) * 64 + lane];
    uint64_t rmv = 0;   // lanes 0..15: accumulated suppression words from kept rows
    const uint64_t below = (lane == 0) ? 0ull : (~0ull >> (64 - lane));
#pragma unroll
    for (int W = 0; W < 16; ++W) {
      const int lo = W << 6;
      uint64_t cur0 = shfl64(rmv, W);
      if (nv <= lo) cur0 = ~0ull;
      else if (nv < lo + 64) cur0 |= (~0ull) << (nv - lo);
      uint64_t kept = ~cur0;
      for (int it = 0; it < 64; ++it) {
        bool pred = (((cur0 >> lane) & 1ull) == 0) && ((colr[W] & kept & below) == 0ull);
        uint64_t kn = __ballot(pred);
        if (kn == kept) break;
        kept = kn;
      }
      if (lane == 0) keepb[W] = kept;
      const int w = lane & 15, g = lane >> 4;
      uint64_t acc = 0;
#pragma unroll
      for (int i2 = 0; i2 < 16; ++i2) {
        const int i = (i2 << 2) + g;
        uint64_t msk = (uint64_t)0 - ((kept >> i) & 1ull);
        acc |= shmP[(lo + i) * 17 + w] & msk;
      }
      acc |= shfl64x(acc, 16);
      acc |= shfl64x(acc, 32);
      if (lane < 16) rmv |= acc;
    }
  }
  __syncthreads();
  uint64_t* sel = shmP;   // reuse
  {
    const int k = t;
    uint64_t comp = 0;
    if (k < KTOP && ((keepb[k >> 6] >> (k & 63)) & 1ull)) {
      unsigned s = __float_as_uint(scw[(size_t)n * KTOP + k]);   // > 0 for kept
      comp = ((uint64_t)s << 10) | (uint64_t)(1023 - k);
    }
    sel[k] = comp;
  }
  __syncthreads();
  bitonic_desc_tpp(sel, 1024, t, 1024);
  if (t < POSTN) {
    const int k = t;
    uint64_t comp = sel[k];
    float x1 = 0, y1 = 0, x2 = 0, y2 = 0, fs = 0;
    int lab = 0;
    if (comp != 0) {
      int i = 1023 - (int)(comp & 0x3FFull);
      fs = __uint_as_float((unsigned)(comp >> 10));
      size_t bb = (size_t)(n * KTOP + i);
      x1 = boxes[bb * 4 + 0]; y1 = boxes[bb * 4 + 1];
      x2 = boxes[bb * 4 + 2]; y2 = boxes[bb * 4 + 3];
      lab = labw[bb];
    }
    float* dr = out + (size_t)(n * POSTN + k) * 5;
    dr[0] = x1; dr[1] = y1; dr[2] = x2; dr[3] = y2; dr[4] = fs;
    out[(size_t)NIMG * POSTN * 5 + (size_t)n * POSTN + k] = (float)lab;
  }
}

extern "C" void kernel_launch(void* const* d_in, const int* in_sizes, int n_in,
                              void* d_out, int out_size, void* d_ws, size_t ws_size,
                              hipStream_t stream) {
  const float* locations = (const float*)d_in[0];
  const float* box_cls = (const float*)d_in[1];
  const float* box_reg = (const float*)d_in[2];
  const float* centerness = (const float*)d_in[3];
  const int* image_sizes = (const int*)d_in[4];
  char* ws = (char*)d_ws;

  unsigned short* h1s = (unsigned short*)(ws + OFF_H1S);
  unsigned short* h2s = (unsigned short*)(ws + OFF_H2S);
  uint64_t* candS = (uint64_t*)(ws + OFF_CANDS);
  unsigned* ccnt = (unsigned*)(ws + OFF_CCNT);
  unsigned* cmaxp = (unsigned*)(ws + OFF_CMAX);
  float* boxes = (float*)(ws + OFF_BOX);
  float* scw = (float*)(ws + OFF_SC);
  int* labw = (int*)(ws + OFF_LAB);
  uint64_t* masks = (uint64_t*)(ws + OFF_MASK);
  uint64_t* colsg = (uint64_t*)(ws + OFF_COLS);
  float* out = (float*)d_out;

  // no memsets: every cross-kernel buffer has exactly one unconditional writer block
  k_hist<<<dim3(NIMG, NSL1), 1024, 0, stream>>>((const float4*)box_cls,
                                                (const float4*)centerness, h1s, cmaxp);
  k_collect<<<dim3(NSL2, NIMG), 1024, 0, stream>>>(h1s, cmaxp, box_cls, centerness,
                                                   candS, ccnt, h2s);
  k_selmask<<<dim3(MSLICE, NIMG), 1024, 0, stream>>>(h1s, h2s, candS, ccnt,
                                                     locations, box_reg, image_sizes,
                                                     boxes, scw, labw, masks, colsg);
  k_scanout<<<NIMG, 1024, 0, stream>>>(masks, colsg, boxes, scw, labw, out);
}

// Round 13
// 130.885 us; speedup vs baseline: 1.7062x; 1.7062x over previous
//
#include <hip/hip_runtime.h>
#include <cstdint>

// ---------------- problem constants ----------------
#define NIMG  16
#define NCLS  80
#define HH    100
#define WW    152
#define HWSZ  (HH*WW)          // 15200
#define HW4   (HWSZ/4)         // 3800
#define NE    (HWSZ*NCLS)      // 1216000
#define KTOP  1000
#define POSTN 100
#define PRE_T 0.05f
#define NMS_T 0.6f
#define FLOOR_KEY 0x3D000000u
#define FLOOR_BIN 976
#define SEL_CAP   2048
#define NTILE 240              // 64-elem chunks per class (238 real + 2 zero-padded)
#define NCHUNK (NCLS*NTILE)    // 19200 chunks per image
#define NSL1  20               // hist1 slices (4 classes each)
#define NSL2  8                // collect slices (2400 chunks each)
#define SCAP  2048             // candidates cap per collect slice
#define MSLICE 16              // mask slices per image (63 rows each)

// ---------------- workspace layout (bytes), ~9.56 MB ----------------
#define OFF_H1S   0u         // u16 [16][20][4096]
#define OFF_H2S   2621440u   // u16 [16][8][4096]
#define OFF_CANDS 3670016u   // u64 [16][8][2048]
#define OFF_CCNT  5767168u   // u32 [16][8]
#define OFF_CMAX  5767680u   // u32 [16][19200]
#define OFF_BOX   6996480u   // f32 [16][1000][4]
#define OFF_SC    7252480u   // f32 [16][1000]
#define OFF_LAB   7316480u   // i32 [16][1000]
#define OFF_MASK  7380480u   // u64 [16][1000][16]  (2,048,000 B)
#define OFF_COLS  9428480u   // u64 [16][16][64]    (131,072 B, ends 9559552)
#define OFF_META  9559552u   // u32 [16][16] {0:thr1,1:cumAbove,3:nv}  -- AFTER colsg!

__device__ __forceinline__ float sigm(float x) { return 1.f / (1.f + expf(-x)); }

__device__ __forceinline__ uint64_t shfl64(uint64_t v, int src) {
  int lo = __shfl((int)(uint32_t)(v & 0xffffffffu), src, 64);
  int hi = __shfl((int)(uint32_t)(v >> 32), src, 64);
  return ((uint64_t)(uint32_t)hi << 32) | (uint32_t)lo;
}
__device__ __forceinline__ uint64_t shfl64x(uint64_t v, int d) {
  int lo = __shfl_xor((int)(uint32_t)(v & 0xffffffffu), d, 64);
  int hi = __shfl_xor((int)(uint32_t)(v >> 32), d, 64);
  return ((uint64_t)(uint32_t)hi << 32) | (uint32_t)lo;
}

// descending bitonic sort, thread-per-pair: one LDS round-trip per pass
__device__ __forceinline__ void bitonic_desc_tpp(uint64_t* s, int nn, int t, int nt) {
  const int np = nn >> 1;
  for (int k2 = 2; k2 <= nn; k2 <<= 1) {
    for (int j = k2 >> 1; j > 0; j >>= 1) {
      __syncthreads();
      for (int q = t; q < np; q += nt) {
        int i = ((q & ~(j - 1)) << 1) | (q & (j - 1));
        int p = i | j;
        uint64_t a = s[i], b = s[p];
        bool desc = ((i & k2) == 0);
        bool sw = desc ? (a < b) : (a > b);
        if (sw) { s[i] = b; s[p] = a; }
      }
    }
  }
  __syncthreads();
}

// Wave-parallel findbin over a 4096-bin LDS histogram, 1024 threads.
// Returns bin = max{b : suffix(b) >= K} (or floorbin if none), cumAbove = suffix(bin+1).
// Equivalent to the serial top-down scan: suffix() is non-increasing in b, so the
// qualifying set is down-closed and its max is unique.
__device__ __forceinline__ void findbin_par(
    const unsigned* __restrict__ hsum, unsigned K, int floorbin, int t,
    unsigned* wtot /*u32[16] LDS*/, int* binmax /*LDS*/, unsigned* cumAb /*LDS*/,
    int* bin_out, unsigned* cumAbove_out) {
  const int lane = t & 63, w = t >> 6;
  const unsigned b0 = hsum[4 * t + 0], b1 = hsum[4 * t + 1];
  const unsigned b2 = hsum[4 * t + 2], b3 = hsum[4 * t + 3];
  unsigned s = b0 + b1 + b2 + b3;
#pragma unroll
  for (int d = 1; d < 64; d <<= 1) {       // in-wave inclusive suffix scan
    unsigned o = (unsigned)__shfl_down((int)s, d, 64);
    if (lane + d < 64) s += o;
  }
  if (lane == 0) wtot[w] = s;              // wave totals
  if (t == 0) *binmax = -1;
  __syncthreads();
  unsigned wafter = 0;
#pragma unroll
  for (int w2 = 1; w2 < 16; ++w2) if (w + w2 < 16) wafter += wtot[w + w2];
  const unsigned s0 = s + wafter;          // suffix(4t)
  const unsigned s1 = s0 - b0;
  const unsigned s2 = s1 - b1;
  const unsigned s3 = s2 - b2;
  int cand = -1;
  if (s3 >= K) cand = 4 * t + 3;
  else if (s2 >= K) cand = 4 * t + 2;
  else if (s1 >= K) cand = 4 * t + 1;
  else if (s0 >= K) cand = 4 * t + 0;
  if (cand >= 0) atomicMax(binmax, cand);
  __syncthreads();
  const int bin = *binmax;
  const int target = (bin >= 0) ? bin : floorbin;
  if (t == (target >> 2)) {
    unsigned suf = ((target & 3) == 0) ? s0 : ((target & 3) == 1) ? s1
                 : ((target & 3) == 2) ? s2 : s3;
    *cumAb = suf - hsum[target];           // suffix(target+1)
  }
  __syncthreads();
  *bin_out = target;
  *cumAbove_out = *cumAb;
}

// ---------------- D1: score histogram slices + per-chunk max keys ----------------
__global__ void __launch_bounds__(1024) k_hist(
    const float4* __restrict__ cls4, const float4* __restrict__ ctr4,
    unsigned short* __restrict__ h1s, unsigned* __restrict__ cmax) {
  __shared__ unsigned h[4096];
  const int n = blockIdx.x, z = blockIdx.y;
  const int t = threadIdx.x;
  for (int i = t; i < 4096; i += 1024) h[i] = 0;
  __syncthreads();
  const float4* cp = cls4 + (size_t)n * (NE / 4);
  const float4* cr = ctr4 + (size_t)n * HW4;
#pragma unroll
  for (int it = 0; it < 4; ++it) {
    const int idx4 = it * 1024 + t;
    const bool val = idx4 < HW4;
    float ct0 = 0, ct1 = 0, ct2 = 0, ct3 = 0;
    if (val) {
      float4 c4 = cr[idx4];
      ct0 = sigm(c4.x); ct1 = sigm(c4.y); ct2 = sigm(c4.z); ct3 = sigm(c4.w);
    }
    const int tile = idx4 >> 4;
    for (int c = z * 4; c < z * 4 + 4; ++c) {
      unsigned k0 = 0, k1 = 0, k2 = 0, k3 = 0;
      if (val) {
        float4 v = cp[c * HW4 + idx4];
        float s0 = sigm(v.x), s1 = sigm(v.y), s2 = sigm(v.z), s3 = sigm(v.w);
        k0 = (s0 > PRE_T) ? __float_as_uint(s0 * ct0) : 0u;
        k1 = (s1 > PRE_T) ? __float_as_uint(s1 * ct1) : 0u;
        k2 = (s2 > PRE_T) ? __float_as_uint(s2 * ct2) : 0u;
        k3 = (s3 > PRE_T) ? __float_as_uint(s3 * ct3) : 0u;
        if (k0 >= FLOOR_KEY) atomicAdd(&h[k0 >> 20], 1u);
        if (k1 >= FLOOR_KEY) atomicAdd(&h[k1 >> 20], 1u);
        if (k2 >= FLOOR_KEY) atomicAdd(&h[k2 >> 20], 1u);
        if (k3 >= FLOOR_KEY) atomicAdd(&h[k3 >> 20], 1u);
      }
      unsigned km = max(max(k0, k1), max(k2, k3));
      km = max(km, (unsigned)__shfl_xor((int)km, 1, 64));
      km = max(km, (unsigned)__shfl_xor((int)km, 2, 64));
      km = max(km, (unsigned)__shfl_xor((int)km, 4, 64));
      km = max(km, (unsigned)__shfl_xor((int)km, 8, 64));
      if ((t & 15) == 0 && tile < NTILE)
        cmax[(size_t)n * NCHUNK + c * NTILE + tile] = km;
    }
  }
  __syncthreads();
  for (int i = t; i < 4096; i += 1024)
    h1s[(size_t)((n * NSL1 + z) << 12) + i] = (unsigned short)h[i];   // <= 60800, fits u16
}

// ---------------- D2: parallel findbin1 + sparse collect into per-slice arrays ----------------
__global__ void __launch_bounds__(1024) k_collect(
    const unsigned short* __restrict__ h1s, const unsigned* __restrict__ cmax,
    const float* __restrict__ cls, const float* __restrict__ ctr,
    uint64_t* __restrict__ candS, unsigned* __restrict__ ccnt,
    unsigned short* __restrict__ h2s, unsigned* __restrict__ meta) {
  __shared__ unsigned hsum[4096];
  __shared__ unsigned h2L[4096];
  __shared__ unsigned queue[2400];
  __shared__ unsigned wtot[16];
  __shared__ int binmax_s;
  __shared__ unsigned cumAb_s;
  __shared__ int qn_s, ccnt_s;
  const int s = blockIdx.x, n = blockIdx.y;
  const int t = threadIdx.x;
  for (int i = t; i < 4096; i += 1024) {
    unsigned v = 0;
    for (int z = 0; z < NSL1; ++z) v += (unsigned)h1s[(size_t)((n * NSL1 + z) << 12) + i];
    hsum[i] = v;
    h2L[i] = 0;
  }
  if (t == 0) { qn_s = 0; ccnt_s = 0; }
  __syncthreads();
  int bin1; unsigned cumAbove;
  findbin_par(hsum, (unsigned)KTOP, FLOOR_BIN, t, wtot, &binmax_s, &cumAb_s, &bin1, &cumAbove);
  if (s == 0 && t == 0) { meta[n * 16 + 0] = (unsigned)bin1; meta[n * 16 + 1] = cumAbove; }
  const unsigned thr1 = (unsigned)bin1, thrKey1 = thr1 << 20;
  const int c0 = s * (NCHUNK / NSL2);                 // 2400 chunks per slice
  for (int i = t; i < NCHUNK / NSL2; i += 1024) {
    if (cmax[(size_t)n * NCHUNK + c0 + i] >= thrKey1) {
      int p = atomicAdd(&qn_s, 1);
      queue[p] = (unsigned)(c0 + i);
    }
  }
  __syncthreads();
  const int qn = qn_s;
  const int lane = t & 63, wv = t >> 6;
  for (int qi = wv; qi < qn; qi += 16) {
    int hc = (int)queue[qi];
    int c = hc / NTILE, tile = hc - c * NTILE;
    int hw = tile * 64 + lane;
    if (hw < HWSZ) {
      float s1 = sigm(cls[((size_t)n * NCLS + c) * HWSZ + hw]);
      float sc = sigm(ctr[(size_t)n * HWSZ + hw]);
      unsigned key = (s1 > PRE_T) ? __float_as_uint(s1 * sc) : 0u;
      if (key >= thrKey1) {
        unsigned fidx = (unsigned)(hw * NCLS + c);
        uint64_t comp = ((uint64_t)key << 21) | (uint64_t)(0x1FFFFFu - fidx);
        int p = atomicAdd(&ccnt_s, 1);
        if (p < SCAP) candS[(size_t)(n * NSL2 + s) * SCAP + p] = comp;
        if ((key >> 20) == thr1) atomicAdd(&h2L[(key >> 8) & 0xFFFu], 1u);
      }
    }
  }
  __syncthreads();
  for (int i = t; i < 4096; i += 1024)
    h2s[(size_t)((n * NSL2 + s) << 12) + i] = (unsigned short)h2L[i];
  if (t == 0) ccnt[n * NSL2 + s] = (unsigned)min(ccnt_s, SCAP);
}

// ---- D3: redundant select/decode per slice + parallel IoU mask (16 blocks/image) ----
__global__ void __launch_bounds__(1024) k_selmask(
    const unsigned short* __restrict__ h2s,
    const uint64_t* __restrict__ candS, const unsigned* __restrict__ ccnt,
    const float* __restrict__ locations, const float* __restrict__ breg,
    const int* __restrict__ imsz, unsigned* __restrict__ meta,
    float* __restrict__ boxes, float* __restrict__ scw, int* __restrict__ labw,
    uint64_t* __restrict__ masks, uint64_t* __restrict__ colsg) {
  __shared__ unsigned h2sum[4096];    // 16 KB (dead after findbin2)
  __shared__ uint64_t sel[SEL_CAP];   // 16 KB (dead after decode)
  __shared__ float4 obs[KTOP];        // 16 KB (live through mask phase)
  __shared__ unsigned wtot[16];
  __shared__ int binmax_s;
  __shared__ unsigned cumAb_s;
  __shared__ int cnt2_s;
  const int slice = blockIdx.x, n = blockIdx.y;
  const int t = threadIdx.x;
  const int lane = t & 63, wv = t >> 6;
  const unsigned thr1 = meta[n * 16 + 0];
  const unsigned cumAbove = meta[n * 16 + 1];

  // ---- sum h2 slices ----
  for (int i = t; i < 4096; i += 1024) {
    unsigned v2 = 0;
    for (int z = 0; z < NSL2; ++z) v2 += (unsigned)h2s[(size_t)((n * NSL2 + z) << 12) + i];
    h2sum[i] = v2;
  }
  if (t == 0) cnt2_s = 0;
  __syncthreads();
  // ---- parallel findbin level 2 (fallback bin=0 <=> thrKey2 = thr1<<20) ----
  int b2; unsigned dumCA;
  findbin_par(h2sum, (unsigned)((int)KTOP - (int)cumAbove), 0, t,
              wtot, &binmax_s, &cumAb_s, &b2, &dumCA);
  const unsigned thrKey2 = (thr1 << 20) | ((unsigned)b2 << 8);

  // ---- gather candidate slices into sel ----
  for (int s = 0; s < NSL2; ++s) {
    const int cn = (int)min(ccnt[n * NSL2 + s], (unsigned)SCAP);
    for (int j = t; j < cn; j += 1024) {
      uint64_t comp = candS[(size_t)(n * NSL2 + s) * SCAP + j];
      if ((unsigned)(comp >> 21) >= thrKey2) {
        int p = atomicAdd(&cnt2_s, 1);
        if (p < SEL_CAP) sel[p] = comp;
      }
    }
  }
  __syncthreads();
  const int m = min(cnt2_s, SEL_CAP);
  const int nn = (m <= 1024) ? 1024 : SEL_CAP;   // deterministic across slices
  for (int j = m + t; j < nn; j += 1024) sel[j] = 0;
  __syncthreads();
  bitonic_desc_tpp(sel, nn, t, 1024);
  const int nv = min(m, KTOP);
  if (slice == 0 && t == 0) meta[n * 16 + 3] = (unsigned)nv;

  // ---- decode boxes (t<1000 one item each); slice 0 writes globals ----
  const float hi = (float)imsz[n * 2 + 0];
  const float wi = (float)imsz[n * 2 + 1];
  const float offmul = fmaxf(wi, hi) + 1.0f;
  if (t < KTOP) {
    const int k = t;
    float x1 = 0, y1 = 0, x2 = 0, y2 = 0, ox1 = 0, oy1 = 0, ox2 = 0, oy2 = 0, s = 0;
    int lab = 0;
    if (k < nv) {
      uint64_t comp = sel[k];
      unsigned key = (unsigned)(comp >> 21);
      unsigned idx = 0x1FFFFFu - (unsigned)(comp & 0x1FFFFFu);
      int hw = (int)(idx / NCLS);
      int c  = (int)(idx - (unsigned)hw * NCLS);
      lab = c + 1;
      float lx = locations[hw * 2 + 0];
      float ly = locations[hw * 2 + 1];
      const float* rg = breg + (size_t)n * 4 * HWSZ;
      float rl = rg[hw], rt = rg[HWSZ + hw], rr = rg[2 * HWSZ + hw], rb = rg[3 * HWSZ + hw];
      x1 = fminf(fmaxf(lx - rl, 0.f), wi - 1.f);
      x2 = fminf(fmaxf(lx + rr, 0.f), wi - 1.f);
      y1 = fminf(fmaxf(ly - rt, 0.f), hi - 1.f);
      y2 = fminf(fmaxf(ly + rb, 0.f), hi - 1.f);
      float off = (float)lab * offmul;
      asm volatile("" : "+v"(off));      // keep the rounded off, forbid fma fusion
      ox1 = x1 + off; oy1 = y1 + off; ox2 = x2 + off; oy2 = y2 + off;
      s = sqrtf(__uint_as_float(key));
    }
    if (slice == 0) {
      size_t bb = (size_t)(n * KTOP + k);
      boxes[bb * 4 + 0] = x1; boxes[bb * 4 + 1] = y1;
      boxes[bb * 4 + 2] = x2; boxes[bb * 4 + 3] = y2;
      scw[bb] = s;
      labw[bb] = lab;
    }
    obs[k] = make_float4(ox1, oy1, ox2, oy2);
  }
  __syncthreads();

  // ---- IoU mask for this slice's 63 rows -> global masks + diagonal columns ----
  for (int rr = wv; rr < 63; rr += 16) {
    const int r = slice * 63 + rr;
    if (r >= nv) continue;                       // wave-uniform branch
    const float4 bi = obs[r];
    float areai = (bi.z - bi.x) * (bi.w - bi.y);
    asm volatile("" : "+v"(areai));
    const int Wr = r >> 6;
    uint64_t* mr = masks + ((size_t)n * KTOP + r) * 16;
    for (int w = 0; w < 16; ++w) {
      int j = (w << 6) + lane;
      bool over = false;
      if (j < nv && j != r) {
        float4 bj = obs[j];
        float areaj = (bj.z - bj.x) * (bj.w - bj.y);
        asm volatile("" : "+v"(areaj));
        float ltx = fmaxf(bi.x, bj.x), lty = fmaxf(bi.y, bj.y);
        float rbx = fminf(bi.z, bj.z), rby = fminf(bi.w, bj.w);
        float wx = fmaxf(rbx - ltx, 0.f), wy = fmaxf(rby - lty, 0.f);
        float inter = wx * wy;
        asm volatile("" : "+v"(inter));
        float denom = areai + areaj - inter + 1e-9f;
        over = (inter / denom) > NMS_T;
      }
      uint64_t bu = __ballot(over && (j > r));
      if (lane == 0) mr[w] = bu;
      if (w == Wr) {
        uint64_t bc = __ballot(over && (j < r));   // column via IoU symmetry
        if (lane == 0) colsg[((size_t)n * 16 + w) * 64 + (r & 63)] = bc;
      }
    }
  }
}

// -------- D4: ballot fixed-point greedy scan + top-100 sort + output (16 blocks) --------
__global__ void __launch_bounds__(1024) k_scanout(
    const uint64_t* __restrict__ masks, const uint64_t* __restrict__ colsg,
    const unsigned* __restrict__ meta,
    const float* __restrict__ boxes, const float* __restrict__ scw,
    const int* __restrict__ labw, float* __restrict__ out) {
  __shared__ uint64_t shmP[KTOP * 17];   // 136,000 B; reused as sel after scan
  __shared__ uint64_t keepb[16];
  const int n = blockIdx.x;
  const int t = threadIdx.x;
  const int lane = t & 63;
  const int nv = (int)meta[n * 16 + 3];
  // stage 1000x16 words, padded rows (stride 17)
  const ulonglong2* src = (const ulonglong2*)(masks + (size_t)n * KTOP * 16);
  for (int j2 = t; j2 < KTOP * 8; j2 += 1024) {
    ulonglong2 v = src[j2];
    int row = j2 >> 3, wp = (j2 & 7) << 1;
    shmP[row * 17 + wp] = v.x;
    shmP[row * 17 + wp + 1] = v.y;
  }
  __syncthreads();
  if (t < 64) {
    uint64_t colr[16];
#pragma unroll
    for (int W = 0; W < 16; ++W) colr[W] = colsg[((size_t)n * 16 + W) * 64 + lane];
    uint64_t rmv = 0;   // lanes 0..15: accumulated suppression words from kept rows
    const uint64_t below = (lane == 0) ? 0ull : (~0ull >> (64 - lane));
#pragma unroll
    for (int W = 0; W < 16; ++W) {
      const int lo = W << 6;
      uint64_t cur0 = shfl64(rmv, W);
      if (nv <= lo) cur0 = ~0ull;
      else if (nv < lo + 64) cur0 |= (~0ull) << (nv - lo);
      uint64_t kept = ~cur0;
      for (int it = 0; it < 64; ++it) {
        bool pred = (((cur0 >> lane) & 1ull) == 0) && ((colr[W] & kept & below) == 0ull);
        uint64_t kn = __ballot(pred);
        if (kn == kept) break;
        kept = kn;
      }
      if (lane == 0) keepb[W] = kept;
      const int w = lane & 15, g = lane >> 4;
      uint64_t acc = 0;
#pragma unroll
      for (int i2 = 0; i2 < 16; ++i2) {
        const int i = (i2 << 2) + g;
        uint64_t msk = (uint64_t)0 - ((kept >> i) & 1ull);
        acc |= shmP[(lo + i) * 17 + w] & msk;
      }
      acc |= shfl64x(acc, 16);
      acc |= shfl64x(acc, 32);
      if (lane < 16) rmv |= acc;
    }
  }
  __syncthreads();
  uint64_t* sel = shmP;   // reuse
  {
    const int k = t;
    uint64_t comp = 0;
    if (k < KTOP && ((keepb[k >> 6] >> (k & 63)) & 1ull)) {
      unsigned s = __float_as_uint(scw[(size_t)n * KTOP + k]);   // > 0 for kept
      comp = ((uint64_t)s << 10) | (uint64_t)(1023 - k);
    }
    sel[k] = comp;
  }
  __syncthreads();
  bitonic_desc_tpp(sel, 1024, t, 1024);
  if (t < POSTN) {
    const int k = t;
    uint64_t comp = sel[k];
    float x1 = 0, y1 = 0, x2 = 0, y2 = 0, fs = 0;
    int lab = 0;
    if (comp != 0) {
      int i = 1023 - (int)(comp & 0x3FFull);
      fs = __uint_as_float((unsigned)(comp >> 10));
      size_t bb = (size_t)(n * KTOP + i);
      x1 = boxes[bb * 4 + 0]; y1 = boxes[bb * 4 + 1];
      x2 = boxes[bb * 4 + 2]; y2 = boxes[bb * 4 + 3];
      lab = labw[bb];
    }
    float* dr = out + (size_t)(n * POSTN + k) * 5;
    dr[0] = x1; dr[1] = y1; dr[2] = x2; dr[3] = y2; dr[4] = fs;
    out[(size_t)NIMG * POSTN * 5 + (size_t)n * POSTN + k] = (float)lab;
  }
}

extern "C" void kernel_launch(void* const* d_in, const int* in_sizes, int n_in,
                              void* d_out, int out_size, void* d_ws, size_t ws_size,
                              hipStream_t stream) {
  const float* locations = (const float*)d_in[0];
  const float* box_cls = (const float*)d_in[1];
  const float* box_reg = (const float*)d_in[2];
  const float* centerness = (const float*)d_in[3];
  const int* image_sizes = (const int*)d_in[4];
  char* ws = (char*)d_ws;

  unsigned short* h1s = (unsigned short*)(ws + OFF_H1S);
  unsigned short* h2s = (unsigned short*)(ws + OFF_H2S);
  uint64_t* candS = (uint64_t*)(ws + OFF_CANDS);
  unsigned* ccnt = (unsigned*)(ws + OFF_CCNT);
  unsigned* cmaxp = (unsigned*)(ws + OFF_CMAX);
  float* boxes = (float*)(ws + OFF_BOX);
  float* scw = (float*)(ws + OFF_SC);
  int* labw = (int*)(ws + OFF_LAB);
  uint64_t* masks = (uint64_t*)(ws + OFF_MASK);
  uint64_t* colsg = (uint64_t*)(ws + OFF_COLS);
  unsigned* meta = (unsigned*)(ws + OFF_META);
  float* out = (float*)d_out;

  // no memsets: every cross-kernel buffer has exactly one unconditional writer block
  k_hist<<<dim3(NIMG, NSL1), 1024, 0, stream>>>((const float4*)box_cls,
                                                (const float4*)centerness, h1s, cmaxp);
  k_collect<<<dim3(NSL2, NIMG), 1024, 0, stream>>>(h1s, cmaxp, box_cls, centerness,
                                                   candS, ccnt, h2s, meta);
  k_selmask<<<dim3(MSLICE, NIMG), 1024, 0, stream>>>(h2s, candS, ccnt,
                                                     locations, box_reg, image_sizes, meta,
                                                     boxes, scw, labw, masks, colsg);
  k_scanout<<<NIMG, 1024, 0, stream>>>(masks, colsg, meta, boxes, scw, labw, out);
}